// Round 1
// baseline (2964.273 us; speedup 1.0000x reference)
//
#include <hip/hip_runtime.h>
#include <cstdint>

constexpr int IN_DIM = 768;

static __device__ __forceinline__ float leaky_(float x){ return x >= 0.0f ? x : 0.01f * x; }

static __device__ __forceinline__ float wsum_(float v){
#pragma unroll
  for (int m = 1; m < 64; m <<= 1) v += __shfl_xor(v, m, 64);
  return v;
}

// LayerNorm across the 64 lanes of a wave (one value per lane).
static __device__ __forceinline__ float wln_(float v, float g, float be){
  float mu  = wsum_(v) * 0.015625f;
  float c   = v - mu;
  float var = wsum_(c * c) * 0.015625f;
  return c * rsqrtf(var + 1e-5f) * g + be;
}

// Encoder: out = LN(leaky(X @ W + b)) for (nrows, 768) @ (768, 64).
// Block = 256 (4 waves), 16 rows/block, each wave does 4 rows, lane = out col.
__global__ __launch_bounds__(256) void k_enc(const float* __restrict__ X,
    const float* __restrict__ W, const float* __restrict__ b,
    const float* __restrict__ g, const float* __restrict__ be,
    float* __restrict__ o0, float* __restrict__ o1, int nrows)
{
  const int w = threadIdx.x >> 6, d = threadIdx.x & 63;
  const int rbase = blockIdx.x * 16 + w * 4;
  int rows[4];
#pragma unroll
  for (int j = 0; j < 4; ++j){ int r = rbase + j; rows[j] = r < nrows ? r : nrows - 1; }
  float acc[4] = {0.f, 0.f, 0.f, 0.f};
  for (int k4 = 0; k4 < IN_DIM / 4; ++k4){
    const int k = k4 * 4;
    const float w0 = W[(k+0)*64+d], w1 = W[(k+1)*64+d];
    const float w2 = W[(k+2)*64+d], w3 = W[(k+3)*64+d];
#pragma unroll
    for (int j = 0; j < 4; ++j){
      const float4 a = *(const float4*)&X[(size_t)rows[j] * IN_DIM + k];
      acc[j] = fmaf(a.x, w0, fmaf(a.y, w1, fmaf(a.z, w2, fmaf(a.w, w3, acc[j]))));
    }
  }
#pragma unroll
  for (int j = 0; j < 4; ++j){
    const int r = rbase + j;
    if (r < nrows){
      float v = wln_(leaky_(acc[j] + b[d]), g[d], be[d]);
      o0[(size_t)r*64+d] = v;
      if (o1) o1[(size_t)r*64+d] = v;
    }
  }
}

// Degree count: cnt[n] = #times n appears in concat([tails, heads]).
__global__ __launch_bounds__(256) void k_cnt(const int* __restrict__ ht,
                                             float* __restrict__ cnt, int M)
{
  int m = blockIdx.x * 256 + threadIdx.x;
  if (m < M){
    atomicAdd(&cnt[ht[2*m+1]], 1.0f);  // tail
    atomicAdd(&cnt[ht[2*m+0]], 1.0f);  // head
  }
}

// Message kernel: per 64-edge tile, stage A = [H[head] | E | H[tail]] (64x192) in LDS,
// compute mf = [Hh,E]@Wf+bf scattered to tails, mb = [Ht,E]@Wb+bb scattered to heads.
// E source: layer0 -> E0 table gathered by relation, layer1 -> E1[m].
__global__ __launch_bounds__(256) void k_msg(
    const float* __restrict__ H, const float* __restrict__ Esrc,
    const float* __restrict__ E0t, const int* __restrict__ rt,
    const int* __restrict__ ht,
    const float* __restrict__ Wf, const float* __restrict__ bf,
    const float* __restrict__ Wb, const float* __restrict__ bb,
    float* __restrict__ agg, int M, int l0)
{
  __shared__ __align__(16) float As[64 * 192];
  const int tile = blockIdx.x * 64;
  // ---- stage 64 edges x 192 floats ----
  for (int idx = threadIdx.x; idx < 64 * 48; idx += 256){
    const int e = idx / 48, c4 = idx % 48;
    int m = tile + e; if (m >= M) m = 0;
    const int h = ht[2*m], t = ht[2*m+1];
    float4 a;
    if (c4 < 16)      a = *(const float4*)&H[(size_t)h * 64 + c4 * 4];
    else if (c4 < 32) a = l0 ? *(const float4*)&E0t[(size_t)rt[m] * 64 + (c4-16)*4]
                             : *(const float4*)&Esrc[(size_t)m * 64 + (c4-16)*4];
    else              a = *(const float4*)&H[(size_t)t * 64 + (c4-32)*4];
    *(float4*)&As[e * 192 + c4 * 4] = a;
  }
  __syncthreads();
  const int w = threadIdx.x >> 6, d = threadIdx.x & 63;
  const int e0 = w * 16;
  float acc[16];
  // ---- mf: A cols 0..127 = [Hh|E], rows 0..127 of Wf ----
#pragma unroll
  for (int e = 0; e < 16; ++e) acc[e] = bf[d];
  for (int k4 = 0; k4 < 32; ++k4){
    const int k = k4 * 4;
    const float w0 = Wf[(k+0)*64+d], w1 = Wf[(k+1)*64+d];
    const float w2 = Wf[(k+2)*64+d], w3 = Wf[(k+3)*64+d];
#pragma unroll
    for (int e = 0; e < 16; ++e){
      const float4 a = *(const float4*)&As[(e0+e)*192 + k];
      acc[e] = fmaf(a.x, w0, fmaf(a.y, w1, fmaf(a.z, w2, fmaf(a.w, w3, acc[e]))));
    }
  }
#pragma unroll
  for (int e = 0; e < 16; ++e){
    const int m = tile + e0 + e;
    if (m < M) atomicAdd(&agg[(size_t)ht[2*m+1] * 64 + d], acc[e]);
  }
  // ---- mb: [Ht,E] -> Wb rows 0..63 use As cols 128.., rows 64..127 use As cols 64.. ----
#pragma unroll
  for (int e = 0; e < 16; ++e) acc[e] = bb[d];
  for (int k4 = 0; k4 < 16; ++k4){
    const int k = k4 * 4;
    const float w0 = Wb[(k+0)*64+d], w1 = Wb[(k+1)*64+d];
    const float w2 = Wb[(k+2)*64+d], w3 = Wb[(k+3)*64+d];
#pragma unroll
    for (int e = 0; e < 16; ++e){
      const float4 a = *(const float4*)&As[(e0+e)*192 + 128 + k];
      acc[e] = fmaf(a.x, w0, fmaf(a.y, w1, fmaf(a.z, w2, fmaf(a.w, w3, acc[e]))));
    }
  }
  for (int k4 = 0; k4 < 16; ++k4){
    const int k = k4 * 4;
    const float w0 = Wb[(64+k+0)*64+d], w1 = Wb[(64+k+1)*64+d];
    const float w2 = Wb[(64+k+2)*64+d], w3 = Wb[(64+k+3)*64+d];
#pragma unroll
    for (int e = 0; e < 16; ++e){
      const float4 a = *(const float4*)&As[(e0+e)*192 + 64 + k];
      acc[e] = fmaf(a.x, w0, fmaf(a.y, w1, fmaf(a.z, w2, fmaf(a.w, w3, acc[e]))));
    }
  }
#pragma unroll
  for (int e = 0; e < 16; ++e){
    const int m = tile + e0 + e;
    if (m < M) atomicAdd(&agg[(size_t)ht[2*m+0] * 64 + d], acc[e]);
  }
}

// H = LN(leaky(agg/cnt) + H). One wave per node row.
__global__ __launch_bounds__(256) void k_hupd(float* __restrict__ H,
    const float* __restrict__ agg, const float* __restrict__ cnt,
    const float* __restrict__ g, const float* __restrict__ be, int N)
{
  const int w = threadIdx.x >> 6, d = threadIdx.x & 63;
  const int n = blockIdx.x * 4 + w;
  if (n >= N) return;
  const float c = cnt[n];
  const float a = agg[(size_t)n*64+d] / c;
  const float v = leaky_(a) + H[(size_t)n*64+d];
  H[(size_t)n*64+d] = wln_(v, g[d], be[d]);
}

// Edge update (layer 0, all edges): Eout = LN(leaky([Hh|E|Ht] @ W + b) + E).
__global__ __launch_bounds__(256) void k_eu(
    const float* __restrict__ H, const float* __restrict__ Esrc,
    const float* __restrict__ E0t, const int* __restrict__ rt,
    const int* __restrict__ ht,
    const float* __restrict__ W, const float* __restrict__ b,
    const float* __restrict__ g, const float* __restrict__ be,
    float* __restrict__ Eout, int M, int l0)
{
  __shared__ __align__(16) float As[64 * 192];
  const int tile = blockIdx.x * 64;
  for (int idx = threadIdx.x; idx < 64 * 48; idx += 256){
    const int e = idx / 48, c4 = idx % 48;
    int m = tile + e; if (m >= M) m = 0;
    const int h = ht[2*m], t = ht[2*m+1];
    float4 a;
    if (c4 < 16)      a = *(const float4*)&H[(size_t)h * 64 + c4 * 4];
    else if (c4 < 32) a = l0 ? *(const float4*)&E0t[(size_t)rt[m] * 64 + (c4-16)*4]
                             : *(const float4*)&Esrc[(size_t)m * 64 + (c4-16)*4];
    else              a = *(const float4*)&H[(size_t)t * 64 + (c4-32)*4];
    *(float4*)&As[e * 192 + c4 * 4] = a;
  }
  __syncthreads();
  const int w = threadIdx.x >> 6, d = threadIdx.x & 63;
  const int e0 = w * 16;
  float acc[16];
#pragma unroll
  for (int e = 0; e < 16; ++e) acc[e] = b[d];
  for (int k4 = 0; k4 < 48; ++k4){
    const int k = k4 * 4;
    const float w0 = W[(k+0)*64+d], w1 = W[(k+1)*64+d];
    const float w2 = W[(k+2)*64+d], w3 = W[(k+3)*64+d];
#pragma unroll
    for (int e = 0; e < 16; ++e){
      const float4 a = *(const float4*)&As[(e0+e)*192 + k];
      acc[e] = fmaf(a.x, w0, fmaf(a.y, w1, fmaf(a.z, w2, fmaf(a.w, w3, acc[e]))));
    }
  }
  for (int e = 0; e < 16; ++e){
    const int m = tile + e0 + e;
    if (m < M){
      const float ep = As[(e0+e)*192 + 64 + d];
      Eout[(size_t)m*64+d] = wln_(leaky_(acc[e]) + ep, g[d], be[d]);
    }
  }
}

// ---- qi = nonzero(queries) compaction (3-phase, order-preserving) ----
__global__ __launch_bounds__(256) void k_qcount(const int* __restrict__ q,
                                                int* __restrict__ bcnt, int M)
{
  const int j = blockIdx.x * 256 + threadIdx.x;
  const int have = (j < M) && (q[j] != 0);
  unsigned long long bal = __ballot(have);
  if ((threadIdx.x & 63) == 0) atomicAdd(&bcnt[blockIdx.x], (int)__popcll(bal));
}

__global__ __launch_bounds__(256) void k_qscan(int* __restrict__ bcnt, int nb)
{
  __shared__ int ws[4];
  const int tid = threadIdx.x, lane = tid & 63, w = tid >> 6;
  const int chunk = (nb + 255) / 256;
  int s = 0;
  for (int i = 0; i < chunk; ++i){ int idx = tid * chunk + i; if (idx < nb) s += bcnt[idx]; }
  int v = s;
#pragma unroll
  for (int off = 1; off < 64; off <<= 1){ int t = __shfl_up(v, off, 64); if (lane >= off) v += t; }
  if (lane == 63) ws[w] = v;
  __syncthreads();
  int wbase = 0;
  for (int i = 0; i < w; ++i) wbase += ws[i];
  int run = wbase + v - s;   // exclusive prefix of this thread
  for (int i = 0; i < chunk; ++i){
    int idx = tid * chunk + i;
    if (idx < nb){ int t = bcnt[idx]; bcnt[idx] = run; run += t; }
  }
}

__global__ __launch_bounds__(256) void k_qemit(const int* __restrict__ q,
    const int* __restrict__ bcnt, int* __restrict__ qi, int M, int NQ)
{
  __shared__ int wb[4];
  const int j = blockIdx.x * 256 + threadIdx.x;
  const int lane = threadIdx.x & 63, w = threadIdx.x >> 6;
  const int have = (j < M) && (q[j] != 0);
  unsigned long long bal = __ballot(have);
  if (lane == 0) wb[w] = (int)__popcll(bal);
  __syncthreads();
  int base = bcnt[blockIdx.x];
  for (int i = 0; i < w; ++i) base += wb[i];
  const int rank = base + (int)__popcll(bal & ((1ull << lane) - 1ull));
  if (have && rank < NQ) qi[rank] = j;
}

// Layer-1 edge update for query rows only + feature assembly.
__global__ __launch_bounds__(256) void k_feat(
    const float* __restrict__ H, const float* __restrict__ H0,
    const float* __restrict__ E1, const float* __restrict__ E0t,
    const int* __restrict__ rt, const int* __restrict__ ht, const int* __restrict__ qi,
    const float* __restrict__ W, const float* __restrict__ b,
    const float* __restrict__ g, const float* __restrict__ be,
    float* __restrict__ feat, int NQ)
{
  const int w = threadIdx.x >> 6, d = threadIdx.x & 63;
  const int row = blockIdx.x * 4 + w;
  if (row >= NQ) return;
  const int m = qi[row];
  const int h = ht[2*m], t = ht[2*m+1], r = rt[m];
  const float* seg0 = H  + (size_t)h * 64;
  const float* seg1 = E1 + (size_t)m * 64;
  const float* seg2 = H  + (size_t)t * 64;
  float acc = b[d];
  for (int k4 = 0; k4 < 48; ++k4){
    const int k = k4 * 4;
    const float* A = (k4 < 16) ? seg0 : (k4 < 32) ? seg1 - 64 : seg2 - 128;
    const float4 a = *(const float4*)&A[k];
    acc = fmaf(a.x, W[(k+0)*64+d], fmaf(a.y, W[(k+1)*64+d],
          fmaf(a.z, W[(k+2)*64+d], fmaf(a.w, W[(k+3)*64+d], acc))));
  }
  const float ep = E1[(size_t)m*64+d];
  const float e2 = wln_(leaky_(acc) + ep, g[d], be[d]);
  float* F = feat + (size_t)row * 384;
  F[      d] = e2;
  F[ 64 + d] = E0t[(size_t)r*64+d];
  F[128 + d] = H [(size_t)h*64+d];
  F[192 + d] = H0[(size_t)h*64+d];
  F[256 + d] = H [(size_t)t*64+d];
  F[320 + d] = H0[(size_t)t*64+d];
}

// out = leaky(feat @ W1 + b1) @ W2 + b2. One wave per query row.
__global__ __launch_bounds__(256) void k_cls(const float* __restrict__ feat,
    const float* __restrict__ W1, const float* __restrict__ b1,
    const float* __restrict__ W2, const float* __restrict__ b2,
    float* __restrict__ out, int NQ)
{
  const int w = threadIdx.x >> 6, d = threadIdx.x & 63;
  const int row = blockIdx.x * 4 + w;
  if (row >= NQ) return;
  const float* F = feat + (size_t)row * 384;
  float acc = b1[d];
  for (int k4 = 0; k4 < 96; ++k4){
    const int k = k4 * 4;
    const float4 a = *(const float4*)&F[k];
    acc = fmaf(a.x, W1[(k+0)*64+d], fmaf(a.y, W1[(k+1)*64+d],
          fmaf(a.z, W1[(k+2)*64+d], fmaf(a.w, W1[(k+3)*64+d], acc))));
  }
  float hs = leaky_(acc) * W2[d];
  hs = wsum_(hs);
  if (d == 0) out[row] = hs + b2[0];
}

extern "C" void kernel_launch(void* const* d_in, const int* in_sizes, int n_in,
                              void* d_out, int out_size, void* d_ws, size_t ws_size,
                              hipStream_t stream)
{
  const int*   ht    = (const int*)  d_in[0];
  const int*   rt    = (const int*)  d_in[1];
  const float* ef    = (const float*)d_in[2];
  const int*   q     = (const int*)  d_in[3];
  const float* rtab  = (const float*)d_in[4];
  const float* W_ent = (const float*)d_in[5];
  const float* b_ent = (const float*)d_in[6];
  const float* g_ent = (const float*)d_in[7];
  const float* be_ent= (const float*)d_in[8];
  const float* W_ein = (const float*)d_in[9];
  const float* b_ein = (const float*)d_in[10];
  const float* g_e   = (const float*)d_in[11];
  const float* be_e  = (const float*)d_in[12];
  const float* mp_Wf = (const float*)d_in[13];
  const float* mp_bf = (const float*)d_in[14];
  const float* mp_Wb = (const float*)d_in[15];
  const float* mp_bb = (const float*)d_in[16];
  const float* mp_g  = (const float*)d_in[17];
  const float* mp_be = (const float*)d_in[18];
  const float* eu_W  = (const float*)d_in[19];
  const float* eu_b  = (const float*)d_in[20];
  const float* eu_g  = (const float*)d_in[21];
  const float* eu_be = (const float*)d_in[22];
  const float* clsW1 = (const float*)d_in[23];
  const float* clsb1 = (const float*)d_in[24];
  const float* clsW2 = (const float*)d_in[25];
  const float* clsb2 = (const float*)d_in[26];

  const int M    = in_sizes[1];
  const int N    = in_sizes[2] / IN_DIM;
  const int NREL = in_sizes[4] / IN_DIM;
  const int NQ   = out_size;
  const int nb   = (M + 255) / 256;

  float* H0   = (float*)d_ws;
  float* H    = H0   + (size_t)N * 64;
  float* agg  = H    + (size_t)N * 64;
  float* E1   = agg  + (size_t)N * 64;
  float* E0t  = E1   + (size_t)M * 64;
  float* feat = E0t  + (size_t)NREL * 64;
  float* cnt  = feat + (size_t)NQ * 384;
  int*   qi   = (int*)(cnt + N);
  int*   bcnt = qi + NQ;

  hipMemsetAsync(cnt,  0, (size_t)N  * 4, stream);
  hipMemsetAsync(qi,   0, (size_t)NQ * 4, stream);
  hipMemsetAsync(bcnt, 0, (size_t)nb * 4, stream);

  // Encoders
  k_enc<<<(N + 15) / 16, 256, 0, stream>>>(ef, W_ent, b_ent, g_ent, be_ent, H0, H, N);
  k_enc<<<(NREL + 15) / 16, 256, 0, stream>>>(rtab, W_ein, b_ein, g_e, be_e, E0t, nullptr, NREL);
  k_cnt<<<(M + 255) / 256, 256, 0, stream>>>(ht, cnt, M);

  const int etiles = (M + 63) / 64;
  // ---- layer 0 ----
  hipMemsetAsync(agg, 0, (size_t)N * 64 * 4, stream);
  k_msg<<<etiles, 256, 0, stream>>>(H, E1, E0t, rt, ht,
      mp_Wf + 0, mp_bf + 0, mp_Wb + 0, mp_bb + 0, agg, M, 1);
  k_hupd<<<(N + 3) / 4, 256, 0, stream>>>(H, agg, cnt, mp_g + 0, mp_be + 0, N);
  k_eu<<<etiles, 256, 0, stream>>>(H, E1, E0t, rt, ht,
      eu_W + 0, eu_b + 0, eu_g + 0, eu_be + 0, E1, M, 1);
  // ---- layer 1 ----
  hipMemsetAsync(agg, 0, (size_t)N * 64 * 4, stream);
  k_msg<<<etiles, 256, 0, stream>>>(H, E1, E0t, rt, ht,
      mp_Wf + 128*64, mp_bf + 64, mp_Wb + 128*64, mp_bb + 64, agg, M, 0);
  k_hupd<<<(N + 3) / 4, 256, 0, stream>>>(H, agg, cnt, mp_g + 64, mp_be + 64, N);
  // layer-1 edge update only needed at query rows -> fused into k_feat.

  // qi compaction
  k_qcount<<<nb, 256, 0, stream>>>(q, bcnt, M);
  k_qscan<<<1, 256, 0, stream>>>(bcnt, nb);
  k_qemit<<<nb, 256, 0, stream>>>(q, bcnt, qi, M, NQ);

  // features + classifier
  k_feat<<<(NQ + 3) / 4, 256, 0, stream>>>(H, H0, E1, E0t, rt, ht, qi,
      eu_W + 192*64, eu_b + 64, eu_g + 64, eu_be + 64, feat, NQ);
  k_cls<<<(NQ + 3) / 4, 256, 0, stream>>>(feat, clsW1, clsb1, clsW2, clsb2,
      (float*)d_out, NQ);
}

// Round 3
// 1875.126 us; speedup vs baseline: 1.5808x; 1.5808x over previous
//
#include <hip/hip_runtime.h>
#include <hip/hip_bf16.h>
#include <cstdint>

constexpr int IN_DIM = 768;

typedef __attribute__((ext_vector_type(8))) short bf16x8;
typedef __attribute__((ext_vector_type(4))) float f32x4;

static __device__ __forceinline__ float leaky_(float x){ return x >= 0.0f ? x : 0.01f * x; }

static __device__ __forceinline__ float wsum_(float v){
#pragma unroll
  for (int m = 1; m < 64; m <<= 1) v += __shfl_xor(v, m, 64);
  return v;
}

static __device__ __forceinline__ float wln_(float v, float g, float be){
  float mu  = wsum_(v) * 0.015625f;
  float c   = v - mu;
  float var = wsum_(c * c) * 0.015625f;
  return c * rsqrtf(var + 1e-5f) * g + be;
}

static __device__ __forceinline__ unsigned short f2bf(float x){
  return __bfloat16_as_ushort(__float2bfloat16(x));
}
static __device__ __forceinline__ float bf2f(unsigned short u){
  return __bfloat162float(__ushort_as_bfloat16(u));
}
static __device__ __forceinline__ void split4(const float4 a, ushort4& hi, ushort4& lo){
  hi.x = f2bf(a.x); lo.x = f2bf(a.x - bf2f(hi.x));
  hi.y = f2bf(a.y); lo.y = f2bf(a.y - bf2f(hi.y));
  hi.z = f2bf(a.z); lo.z = f2bf(a.z - bf2f(hi.z));
  hi.w = f2bf(a.w); lo.w = f2bf(a.w - bf2f(hi.w));
}

// ---------------- weight prep: split-bf16 fragment tables ----------------
// Frag layout (16x16x32 B-operand): frag (kt,n): lane l holds
// W[kt*32 + (l>>4)*8 + j][n*16 + (l&15)], j=0..7, stored contiguous ushort8.
// Table: [Wf0:16][Wb0:16][Wf1:16][Wb1:16][euW0:24] frags, 512 ushort each.
__global__ __launch_bounds__(256) void k_wprep(
    const float* __restrict__ Wf, const float* __restrict__ Wb,
    const float* __restrict__ euW,
    unsigned short* __restrict__ Fhi, unsigned short* __restrict__ Flo)
{
  const int gt = blockIdx.x * 256 + threadIdx.x;
  if (gt >= 88 * 64) return;
  const int fid = gt >> 6, lane = gt & 63;
  const float* src; int lf;
  if (fid < 16)      { src = Wf;            lf = fid;      }
  else if (fid < 32) { src = Wb;            lf = fid - 16; }
  else if (fid < 48) { src = Wf + 128 * 64; lf = fid - 32; }
  else if (fid < 64) { src = Wb + 128 * 64; lf = fid - 48; }
  else               { src = euW;           lf = fid - 64; }
  const int kt = lf >> 2, n = lf & 3;
  const int col = n * 16 + (lane & 15);
  const int r0  = kt * 32 + (lane >> 4) * 8;
  unsigned short* ph = Fhi + ((size_t)fid << 9) + lane * 8;
  unsigned short* pl = Flo + ((size_t)fid << 9) + lane * 8;
#pragma unroll
  for (int j = 0; j < 8; ++j){
    const float v = src[(size_t)(r0 + j) * 64 + col];
    const unsigned short h = f2bf(v);
    ph[j] = h;
    pl[j] = f2bf(v - bf2f(h));
  }
}

// ---------------- shared staging: A = [H[head] | E | H[tail]] split-bf16 ----------------
// Ahi/Alo: [64 rows][192 cols] bf16, XOR-swizzled: byte ^= (row&7)<<4.
// 64 rows x 48 float4-chunks (4 elems each) = 3072 tasks = 12 x 256 threads.
static __device__ __forceinline__ void stage_tile(
    unsigned short* Ahi, unsigned short* Alo,
    const float* __restrict__ H, const float* __restrict__ Esrc,
    const float* __restrict__ E0t, const int* __restrict__ rt,
    const int* __restrict__ ht, int tile, int M, int l0, int tid)
{
#pragma unroll
  for (int i = 0; i < 12; ++i){
    const int idx = tid + 256 * i;
    const int row = idx / 48, c = idx % 48;
    int m = tile + row; if (m >= M) m = 0;
    const int h = ht[2*m], t = ht[2*m+1];
    const int cc = c & 15;
    float4 a;
    if (c < 16)      a = *(const float4*)&H[(size_t)h * 64 + cc * 4];
    else if (c < 32) a = l0 ? *(const float4*)&E0t[(size_t)rt[m] * 64 + cc * 4]
                            : *(const float4*)&Esrc[(size_t)m * 64 + cc * 4];
    else             a = *(const float4*)&H[(size_t)t * 64 + cc * 4];
    ushort4 hi, lo; split4(a, hi, lo);
    const int ad = (row * 384 + c * 8) ^ ((row & 7) << 4);
    *(ushort4*)((char*)Ahi + ad) = hi;
    *(ushort4*)((char*)Alo + ad) = lo;
  }
}

// ---------------- message kernel (MFMA, split bf16) ----------------
// 4 waves: w0,w1 -> mf (edges 0-31 / 32-63), w2,w3 -> mb.
// mf: A k-tiles {0,1,2,3} x Wf; mb: A k-tiles {4,5,2,3} x Wb (Ht then E).
__global__ __launch_bounds__(256) void k_msg(
    const float* __restrict__ H, const float* __restrict__ Esrc,
    const float* __restrict__ E0t, const int* __restrict__ rt,
    const int* __restrict__ ht,
    const unsigned short* __restrict__ Fhi, const unsigned short* __restrict__ Flo,
    const float* __restrict__ bf, const float* __restrict__ bb,
    float* __restrict__ agg, int M, int l0, int fbf, int fbb)
{
  __shared__ unsigned short Ahi[64 * 192];
  __shared__ unsigned short Alo[64 * 192];
  const int tile = blockIdx.x * 64;
  const int tid = threadIdx.x;
  stage_tile(Ahi, Alo, H, Esrc, E0t, rt, ht, tile, M, l0, tid);
  __syncthreads();

  const int w = tid >> 6, lane = tid & 63;
  const int wtype = w >> 1;             // 0 = mf, 1 = mb
  const int ebase = (w & 1) * 32;
  const int g = lane >> 4, lr = lane & 15;

  bf16x8 Ah[2][4], Al[2][4];
#pragma unroll
  for (int mt = 0; mt < 2; ++mt)
#pragma unroll
    for (int kt = 0; kt < 4; ++kt){
      const int at = (kt < 2) ? (wtype ? 4 + kt : kt) : kt;
      const int row = ebase + mt * 16 + lr;
      const int ad = (row * 384 + at * 64 + g * 16) ^ ((row & 7) << 4);
      Ah[mt][kt] = *(const bf16x8*)((const char*)Ahi + ad);
      Al[mt][kt] = *(const bf16x8*)((const char*)Alo + ad);
    }

  const int fb = wtype ? fbb : fbf;
  const float* bias = wtype ? bb : bf;
  f32x4 acc[2][4];
#pragma unroll
  for (int n = 0; n < 4; ++n){
    const float bv = bias[n * 16 + lr];
#pragma unroll
    for (int mt = 0; mt < 2; ++mt) acc[mt][n] = (f32x4){bv, bv, bv, bv};
  }

#pragma unroll
  for (int n = 0; n < 4; ++n)
#pragma unroll
    for (int kt = 0; kt < 4; ++kt){
      const size_t fo = (((size_t)(fb + kt * 4 + n)) << 9) + lane * 8;
      const bf16x8 wh = *(const bf16x8*)(Fhi + fo);
      const bf16x8 wl = *(const bf16x8*)(Flo + fo);
#pragma unroll
      for (int mt = 0; mt < 2; ++mt){
        acc[mt][n] = __builtin_amdgcn_mfma_f32_16x16x32_bf16(Ah[mt][kt], wh, acc[mt][n], 0, 0, 0);
        acc[mt][n] = __builtin_amdgcn_mfma_f32_16x16x32_bf16(Al[mt][kt], wh, acc[mt][n], 0, 0, 0);
        acc[mt][n] = __builtin_amdgcn_mfma_f32_16x16x32_bf16(Ah[mt][kt], wl, acc[mt][n], 0, 0, 0);
      }
    }

  const int sel = wtype ? 0 : 1;        // mf -> tail, mb -> head
#pragma unroll
  for (int mt = 0; mt < 2; ++mt)
#pragma unroll
    for (int reg = 0; reg < 4; ++reg){
      const int e = tile + ebase + mt * 16 + g * 4 + reg;
      if (e < M){
        const int dst = ht[2 * e + sel];
        float* ap = agg + (size_t)dst * 64 + lr;
#pragma unroll
        for (int n = 0; n < 4; ++n) atomicAdd(ap + n * 16, acc[mt][n][reg]);
      }
    }
}

// ---------------- edge update (MFMA, split bf16): Eout = LN(leaky(A@W+b)+E) ----------------
__global__ __launch_bounds__(256) void k_eu(
    const float* __restrict__ H, const float* __restrict__ Esrc,
    const float* __restrict__ E0t, const int* __restrict__ rt,
    const int* __restrict__ ht,
    const unsigned short* __restrict__ Fhi, const unsigned short* __restrict__ Flo, int fb,
    const float* __restrict__ b, const float* __restrict__ g_,
    const float* __restrict__ be, float* __restrict__ Eout, int M, int l0)
{
  __shared__ unsigned short Ahi[64 * 192];
  __shared__ unsigned short Alo[64 * 192];
  const int tile = blockIdx.x * 64;
  const int tid = threadIdx.x;
  stage_tile(Ahi, Alo, H, Esrc, E0t, rt, ht, tile, M, l0, tid);
  __syncthreads();

  const int w = tid >> 6, lane = tid & 63;
  const int g = lane >> 4, lr = lane & 15;
  const int rowb = w * 16;

  bf16x8 Ah[6], Al[6];
#pragma unroll
  for (int kt = 0; kt < 6; ++kt){
    const int row = rowb + lr;
    const int ad = (row * 384 + kt * 64 + g * 16) ^ ((row & 7) << 4);
    Ah[kt] = *(const bf16x8*)((const char*)Ahi + ad);
    Al[kt] = *(const bf16x8*)((const char*)Alo + ad);
  }

  f32x4 acc[4];
#pragma unroll
  for (int n = 0; n < 4; ++n){
    const float bv = b[n * 16 + lr];
    acc[n] = (f32x4){bv, bv, bv, bv};
  }
#pragma unroll
  for (int n = 0; n < 4; ++n)
#pragma unroll
    for (int kt = 0; kt < 6; ++kt){
      const size_t fo = (((size_t)(fb + kt * 4 + n)) << 9) + lane * 8;
      const bf16x8 wh = *(const bf16x8*)(Fhi + fo);
      const bf16x8 wl = *(const bf16x8*)(Flo + fo);
      acc[n] = __builtin_amdgcn_mfma_f32_16x16x32_bf16(Ah[kt], wh, acc[n], 0, 0, 0);
      acc[n] = __builtin_amdgcn_mfma_f32_16x16x32_bf16(Al[kt], wh, acc[n], 0, 0, 0);
      acc[n] = __builtin_amdgcn_mfma_f32_16x16x32_bf16(Ah[kt], wl, acc[n], 0, 0, 0);
    }

  // epilogue: leaky + residual (E reconstructed from hi+lo in LDS) + LN over 64 cols
#pragma unroll
  for (int reg = 0; reg < 4; ++reg){
    const int lrow = rowb + g * 4 + reg;
    float v[4];
#pragma unroll
    for (int n = 0; n < 4; ++n){
      const int col = n * 16 + lr;
      const int ad2 = (lrow * 384 + 128 + 2 * col) ^ ((lrow & 7) << 4);
      const float ep = bf2f(*(const unsigned short*)((const char*)Ahi + ad2))
                     + bf2f(*(const unsigned short*)((const char*)Alo + ad2));
      v[n] = leaky_(acc[n][reg]) + ep;
    }
    float s = v[0] + v[1] + v[2] + v[3];
#pragma unroll
    for (int msk = 1; msk < 16; msk <<= 1) s += __shfl_xor(s, msk, 64);
    const float mu = s * 0.015625f;
    float q = 0.f;
#pragma unroll
    for (int n = 0; n < 4; ++n){ v[n] -= mu; q += v[n] * v[n]; }
#pragma unroll
    for (int msk = 1; msk < 16; msk <<= 1) q += __shfl_xor(q, msk, 64);
    const float rs = rsqrtf(q * 0.015625f + 1e-5f);
    const int e = tile + lrow;
    if (e < M){
#pragma unroll
      for (int n = 0; n < 4; ++n){
        const int col = n * 16 + lr;
        Eout[(size_t)e * 64 + col] = v[n] * rs * g_[col] + be[col];
      }
    }
  }
}

// ---------------- f32 kernels kept from R1 ----------------
__global__ __launch_bounds__(256) void k_enc(const float* __restrict__ X,
    const float* __restrict__ W, const float* __restrict__ b,
    const float* __restrict__ g, const float* __restrict__ be,
    float* __restrict__ o0, float* __restrict__ o1, int nrows)
{
  const int w = threadIdx.x >> 6, d = threadIdx.x & 63;
  const int rbase = blockIdx.x * 16 + w * 4;
  int rows[4];
#pragma unroll
  for (int j = 0; j < 4; ++j){ int r = rbase + j; rows[j] = r < nrows ? r : nrows - 1; }
  float acc[4] = {0.f, 0.f, 0.f, 0.f};
  for (int k4 = 0; k4 < IN_DIM / 4; ++k4){
    const int k = k4 * 4;
    const float w0 = W[(k+0)*64+d], w1 = W[(k+1)*64+d];
    const float w2 = W[(k+2)*64+d], w3 = W[(k+3)*64+d];
#pragma unroll
    for (int j = 0; j < 4; ++j){
      const float4 a = *(const float4*)&X[(size_t)rows[j] * IN_DIM + k];
      acc[j] = fmaf(a.x, w0, fmaf(a.y, w1, fmaf(a.z, w2, fmaf(a.w, w3, acc[j]))));
    }
  }
#pragma unroll
  for (int j = 0; j < 4; ++j){
    const int r = rbase + j;
    if (r < nrows){
      float v = wln_(leaky_(acc[j] + b[d]), g[d], be[d]);
      o0[(size_t)r*64+d] = v;
      if (o1) o1[(size_t)r*64+d] = v;
    }
  }
}

__global__ __launch_bounds__(256) void k_cnt(const int* __restrict__ ht,
                                             float* __restrict__ cnt, int M)
{
  int m = blockIdx.x * 256 + threadIdx.x;
  if (m < M){
    atomicAdd(&cnt[ht[2*m+1]], 1.0f);
    atomicAdd(&cnt[ht[2*m+0]], 1.0f);
  }
}

__global__ __launch_bounds__(256) void k_hupd(float* __restrict__ H,
    const float* __restrict__ agg, const float* __restrict__ cnt,
    const float* __restrict__ g, const float* __restrict__ be, int N)
{
  const int w = threadIdx.x >> 6, d = threadIdx.x & 63;
  const int n = blockIdx.x * 4 + w;
  if (n >= N) return;
  const float c = cnt[n];
  const float a = agg[(size_t)n*64+d] / c;
  const float v = leaky_(a) + H[(size_t)n*64+d];
  H[(size_t)n*64+d] = wln_(v, g[d], be[d]);
}

__global__ __launch_bounds__(256) void k_qcount(const int* __restrict__ q,
                                                int* __restrict__ bcnt, int M)
{
  const int j = blockIdx.x * 256 + threadIdx.x;
  const int have = (j < M) && (q[j] != 0);
  unsigned long long bal = __ballot(have);
  if ((threadIdx.x & 63) == 0) atomicAdd(&bcnt[blockIdx.x], (int)__popcll(bal));
}

__global__ __launch_bounds__(256) void k_qscan(int* __restrict__ bcnt, int nb)
{
  __shared__ int ws[4];
  const int tid = threadIdx.x, lane = tid & 63, w = tid >> 6;
  const int chunk = (nb + 255) / 256;
  int s = 0;
  for (int i = 0; i < chunk; ++i){ int idx = tid * chunk + i; if (idx < nb) s += bcnt[idx]; }
  int v = s;
#pragma unroll
  for (int off = 1; off < 64; off <<= 1){ int t = __shfl_up(v, off, 64); if (lane >= off) v += t; }
  if (lane == 63) ws[w] = v;
  __syncthreads();
  int wbase = 0;
  for (int i = 0; i < w; ++i) wbase += ws[i];
  int run = wbase + v - s;
  for (int i = 0; i < chunk; ++i){
    int idx = tid * chunk + i;
    if (idx < nb){ int t = bcnt[idx]; bcnt[idx] = run; run += t; }
  }
}

__global__ __launch_bounds__(256) void k_qemit(const int* __restrict__ q,
    const int* __restrict__ bcnt, int* __restrict__ qi, int M, int NQ)
{
  __shared__ int wb[4];
  const int j = blockIdx.x * 256 + threadIdx.x;
  const int lane = threadIdx.x & 63, w = threadIdx.x >> 6;
  const int have = (j < M) && (q[j] != 0);
  unsigned long long bal = __ballot(have);
  if (lane == 0) wb[w] = (int)__popcll(bal);
  __syncthreads();
  int base = bcnt[blockIdx.x];
  for (int i = 0; i < w; ++i) base += wb[i];
  const int rank = base + (int)__popcll(bal & ((1ull << lane) - 1ull));
  if (have && rank < NQ) qi[rank] = j;
}

__global__ __launch_bounds__(256) void k_feat(
    const float* __restrict__ H, const float* __restrict__ H0,
    const float* __restrict__ E1, const float* __restrict__ E0t,
    const int* __restrict__ rt, const int* __restrict__ ht, const int* __restrict__ qi,
    const float* __restrict__ W, const float* __restrict__ b,
    const float* __restrict__ g, const float* __restrict__ be,
    float* __restrict__ feat, int NQ)
{
  const int w = threadIdx.x >> 6, d = threadIdx.x & 63;
  const int row = blockIdx.x * 4 + w;
  if (row >= NQ) return;
  const int m = qi[row];
  const int h = ht[2*m], t = ht[2*m+1], r = rt[m];
  const float* seg0 = H  + (size_t)h * 64;
  const float* seg1 = E1 + (size_t)m * 64;
  const float* seg2 = H  + (size_t)t * 64;
  float acc = b[d];
  for (int k4 = 0; k4 < 48; ++k4){
    const int k = k4 * 4;
    const float* A = (k4 < 16) ? seg0 : (k4 < 32) ? seg1 - 64 : seg2 - 128;
    const float4 a = *(const float4*)&A[k];
    acc = fmaf(a.x, W[(k+0)*64+d], fmaf(a.y, W[(k+1)*64+d],
          fmaf(a.z, W[(k+2)*64+d], fmaf(a.w, W[(k+3)*64+d], acc))));
  }
  const float ep = E1[(size_t)m*64+d];
  const float e2 = wln_(leaky_(acc) + ep, g[d], be[d]);
  float* F = feat + (size_t)row * 384;
  F[      d] = e2;
  F[ 64 + d] = E0t[(size_t)r*64+d];
  F[128 + d] = H [(size_t)h*64+d];
  F[192 + d] = H0[(size_t)h*64+d];
  F[256 + d] = H [(size_t)t*64+d];
  F[320 + d] = H0[(size_t)t*64+d];
}

__global__ __launch_bounds__(256) void k_cls(const float* __restrict__ feat,
    const float* __restrict__ W1, const float* __restrict__ b1,
    const float* __restrict__ W2, const float* __restrict__ b2,
    float* __restrict__ out, int NQ)
{
  const int w = threadIdx.x >> 6, d = threadIdx.x & 63;
  const int row = blockIdx.x * 4 + w;
  if (row >= NQ) return;
  const float* F = feat + (size_t)row * 384;
  float acc = b1[d];
  for (int k4 = 0; k4 < 96; ++k4){
    const int k = k4 * 4;
    const float4 a = *(const float4*)&F[k];
    acc = fmaf(a.x, W1[(k+0)*64+d], fmaf(a.y, W1[(k+1)*64+d],
          fmaf(a.z, W1[(k+2)*64+d], fmaf(a.w, W1[(k+3)*64+d], acc))));
  }
  float hs = leaky_(acc) * W2[d];
  hs = wsum_(hs);
  if (d == 0) out[row] = hs + b2[0];
}

extern "C" void kernel_launch(void* const* d_in, const int* in_sizes, int n_in,
                              void* d_out, int out_size, void* d_ws, size_t ws_size,
                              hipStream_t stream)
{
  const int*   ht    = (const int*)  d_in[0];
  const int*   rt    = (const int*)  d_in[1];
  const float* ef    = (const float*)d_in[2];
  const int*   q     = (const int*)  d_in[3];
  const float* rtab  = (const float*)d_in[4];
  const float* W_ent = (const float*)d_in[5];
  const float* b_ent = (const float*)d_in[6];
  const float* g_ent = (const float*)d_in[7];
  const float* be_ent= (const float*)d_in[8];
  const float* W_ein = (const float*)d_in[9];
  const float* b_ein = (const float*)d_in[10];
  const float* g_e   = (const float*)d_in[11];
  const float* be_e  = (const float*)d_in[12];
  const float* mp_Wf = (const float*)d_in[13];
  const float* mp_bf = (const float*)d_in[14];
  const float* mp_Wb = (const float*)d_in[15];
  const float* mp_bb = (const float*)d_in[16];
  const float* mp_g  = (const float*)d_in[17];
  const float* mp_be = (const float*)d_in[18];
  const float* eu_W  = (const float*)d_in[19];
  const float* eu_b  = (const float*)d_in[20];
  const float* eu_g  = (const float*)d_in[21];
  const float* eu_be = (const float*)d_in[22];
  const float* clsW1 = (const float*)d_in[23];
  const float* clsb1 = (const float*)d_in[24];
  const float* clsW2 = (const float*)d_in[25];
  const float* clsb2 = (const float*)d_in[26];

  const int M    = in_sizes[1];
  const int N    = in_sizes[2] / IN_DIM;
  const int NREL = in_sizes[4] / IN_DIM;
  const int NQ   = out_size;
  const int nb   = (M + 255) / 256;

  // workspace layout: frag tables first (16B aligned), then f32 buffers
  unsigned short* Fhi = (unsigned short*)d_ws;          // 88*512 ushorts
  unsigned short* Flo = Fhi + 88 * 512;
  float* H0   = (float*)(Fhi + 2 * 88 * 512);
  float* H    = H0   + (size_t)N * 64;
  float* agg  = H    + (size_t)N * 64;
  float* E1   = agg  + (size_t)N * 64;
  float* E0t  = E1   + (size_t)M * 64;
  float* feat = E0t  + (size_t)NREL * 64;
  float* cnt  = feat + (size_t)NQ * 384;
  int*   qi   = (int*)(cnt + N);
  int*   bcnt = qi + NQ;

  hipMemsetAsync(cnt,  0, (size_t)N  * 4, stream);
  hipMemsetAsync(qi,   0, (size_t)NQ * 4, stream);
  hipMemsetAsync(bcnt, 0, (size_t)nb * 4, stream);

  k_wprep<<<22, 256, 0, stream>>>(mp_Wf, mp_Wb, eu_W, Fhi, Flo);
  k_enc<<<(N + 15) / 16, 256, 0, stream>>>(ef, W_ent, b_ent, g_ent, be_ent, H0, H, N);
  k_enc<<<(NREL + 15) / 16, 256, 0, stream>>>(rtab, W_ein, b_ein, g_e, be_e, E0t, nullptr, NREL);
  k_cnt<<<(M + 255) / 256, 256, 0, stream>>>(ht, cnt, M);

  const int etiles = (M + 63) / 64;
  // ---- layer 0 ----
  hipMemsetAsync(agg, 0, (size_t)N * 64 * 4, stream);
  k_msg<<<etiles, 256, 0, stream>>>(H, E1, E0t, rt, ht, Fhi, Flo,
      mp_bf + 0, mp_bb + 0, agg, M, 1, 0, 16);
  k_hupd<<<(N + 3) / 4, 256, 0, stream>>>(H, agg, cnt, mp_g + 0, mp_be + 0, N);
  k_eu<<<etiles, 256, 0, stream>>>(H, E1, E0t, rt, ht, Fhi, Flo, 64,
      eu_b + 0, eu_g + 0, eu_be + 0, E1, M, 1);
  // ---- layer 1 ----
  hipMemsetAsync(agg, 0, (size_t)N * 64 * 4, stream);
  k_msg<<<etiles, 256, 0, stream>>>(H, E1, E0t, rt, ht, Fhi, Flo,
      mp_bf + 64, mp_bb + 64, agg, M, 0, 32, 48);
  k_hupd<<<(N + 3) / 4, 256, 0, stream>>>(H, agg, cnt, mp_g + 64, mp_be + 64, N);

  // qi compaction
  k_qcount<<<nb, 256, 0, stream>>>(q, bcnt, M);
  k_qscan<<<1, 256, 0, stream>>>(bcnt, nb);
  k_qemit<<<nb, 256, 0, stream>>>(q, bcnt, qi, M, NQ);

  // features + classifier (layer-1 edge update fused at query rows, f32)
  k_feat<<<(NQ + 3) / 4, 256, 0, stream>>>(H, H0, E1, E0t, rt, ht, qi,
      eu_W + 192*64, eu_b + 64, eu_g + 64, eu_be + 64, feat, NQ);
  k_cls<<<(NQ + 3) / 4, 256, 0, stream>>>(feat, clsW1, clsb1, clsW2, clsb2,
      (float*)d_out, NQ);
}